// Round 2
// baseline (416.946 us; speedup 1.0000x reference)
//
#include <hip/hip_runtime.h>

// DecisionTree inference, MI355X.
// 4M samples x 16 features, complete depth-10 tree (1023 internal nodes,
// leaves [1023,2047)), out = tree_value[leaf] (10 floats/sample).
//
// v3: fixes v2's epilogue bug (float4 spanning two 40B sample rows read the
// LDS pad). 5 samples/thread ILP; X in registers + cndmask 16-way select;
// leaf table in LDS (48 KB, rows padded to 12 floats); branchless
// row-spanning float4 epilogue.
// Memory floor: 256 MB read + 160 MB write ~= 66 us @6.3 TB/s.

#define BLOCK 256
#define SPT   5                     // 256*5=1280 samples/block; 4M/1280=3125 exact

constexpr int kFeat     = 16;
constexpr int kCls      = 10;
constexpr int kDepth    = 10;
constexpr int kInternal = 1023;     // nodes [0,1023) internal
constexpr int kLeaves   = 1024;     // rows [1023,2047)
constexpr int kLeafPad  = 12;       // padded LDS row stride (floats) -> 48 B rows
constexpr int kNS       = BLOCK * SPT;          // 1280 samples/block
constexpr int kOutVec4  = kNS * kCls / 4;       // 3200 float4 per block

struct FT { int feat; float thr; }; // 8 B -> one ds_read_b64 per level

// 1-of-16 select by 4-bit index; all register refs compile-time (no scratch).
__device__ __forceinline__ float sel16(float4 a, float4 b, float4 c, float4 d, int f) {
    const bool b0 = f & 1, b1 = f & 2, b2 = f & 4, b3 = f & 8;
    float a01 = b0 ? a.y : a.x, a23 = b0 ? a.w : a.z;
    float b01 = b0 ? b.y : b.x, b23 = b0 ? b.w : b.z;
    float c01 = b0 ? c.y : c.x, c23 = b0 ? c.w : c.z;
    float d01 = b0 ? d.y : d.x, d23 = b0 ? d.w : d.z;
    float av = b1 ? a23 : a01, bv = b1 ? b23 : b01;
    float cv = b1 ? c23 : c01, dv = b1 ? d23 : d01;
    float ab = b2 ? bv : av,   cd = b2 ? dv : cv;
    return b3 ? cd : ab;
}

__global__ __launch_bounds__(BLOCK) void dtree_kernel(
    const float* __restrict__ X,
    const int*   __restrict__ tfeat,
    const float* __restrict__ tthr,
    const float* __restrict__ tval,
    float*       __restrict__ out,
    int n)
{
    __shared__ FT    s_node[kInternal + 1];          //  8 KB
    __shared__ float s_leaf[kLeaves * kLeafPad];     // 48 KB
    __shared__ int   s_leafidx[kNS];                 //  5 KB

    const int tid = threadIdx.x;
    const long long base = (long long)blockIdx.x * kNS;
    const bool fullblk = (base + kNS <= (long long)n);

    // ---- X into registers: 20 independent dwordx4, issued up-front ----
    float4 xr[SPT][4];
    #pragma unroll
    for (int s = 0; s < SPT; ++s) {
        const long long smp = base + (long long)s * BLOCK + tid;
        if (fullblk || smp < (long long)n) {
            const float4* xp = reinterpret_cast<const float4*>(X) + smp * 4;
            xr[s][0] = xp[0]; xr[s][1] = xp[1]; xr[s][2] = xp[2]; xr[s][3] = xp[3];
        } else {
            xr[s][0] = xr[s][1] = xr[s][2] = xr[s][3] = make_float4(0.f, 0.f, 0.f, 0.f);
        }
    }

    // ---- stage internal nodes: 1023 * 8 B ----
    for (int i = tid; i < kInternal; i += BLOCK) {
        FT nd; nd.feat = tfeat[i]; nd.thr = tthr[i];
        s_node[i] = nd;
    }

    // ---- stage leaf rows [1023,2047) padded to 12 floats (8B-granule loads) ----
    #pragma unroll
    for (int k = 0; k < kLeaves / BLOCK; ++k) {      // 4 rows/thread
        const int r = k * BLOCK + tid;               // 0..1023
        const float2* src = reinterpret_cast<const float2*>(
            tval + (long long)(kInternal + r) * kCls);
        float* dst = s_leaf + r * kLeafPad;
        #pragma unroll
        for (int g = 0; g < 5; ++g) {                // 5 * 8 B = 40 B, exact
            float2 v = src[g];
            *reinterpret_cast<float2*>(dst + 2 * g) = v;
        }
    }
    __syncthreads();

    // ---- traversal: 10 levels, 5 interleaved independent chains ----
    int node[SPT];
    #pragma unroll
    for (int s = 0; s < SPT; ++s) node[s] = 0;

    #pragma unroll
    for (int d = 0; d < kDepth; ++d) {
        FT nd[SPT];
        #pragma unroll
        for (int s = 0; s < SPT; ++s) nd[s] = s_node[node[s]];   // 5 indep b64 reads
        #pragma unroll
        for (int s = 0; s < SPT; ++s) {
            const float x = sel16(xr[s][0], xr[s][1], xr[s][2], xr[s][3], nd[s].feat);
            node[s] = 2 * node[s] + 1 + ((x <= nd[s].thr) ? 0 : 1);
        }
    }
    // node[s] in [1023, 2047)

    #pragma unroll
    for (int s = 0; s < SPT; ++s)
        s_leafidx[s * BLOCK + tid] = node[s] - kInternal;        // leaf-local row
    __syncthreads();

    // ---- epilogue: coalesced float4 stores from the LDS leaf table.
    // Output floats for this block: 12800; float4 j covers floats [4j,4j+4).
    // 4j mod 10 in {0,2,4,6,8}. For c0<=6 both halves are in row sib; for
    // c0==8 the second float2 is classes 0,1 of sample sib+1 (branchless). ----
    float* gout = out + base * kCls;
    if (fullblk) {
        for (int j = tid; j < kOutVec4; j += BLOCK) {            // 3200 float4
            const int sib = (2 * j) / 5;                         // = 4j/10 (const div)
            const int c0  = 4 * j - 10 * sib;                    // 0,2,4,6,8
            const bool span = (c0 == 8);
            const int sib1 = span ? sib + 1 : sib;               // sib+1 <= 1279
            const int off1 = span ? 0 : c0 + 2;
            const float2 u0 = *reinterpret_cast<const float2*>(
                s_leaf + s_leafidx[sib]  * kLeafPad + c0);
            const float2 u1 = *reinterpret_cast<const float2*>(
                s_leaf + s_leafidx[sib1] * kLeafPad + off1);
            reinterpret_cast<float4*>(gout)[j] = make_float4(u0.x, u0.y, u1.x, u1.y);
        }
    } else {
        const long long nsValid = (long long)n - base;           // < kNS
        const long long fvalid  = (nsValid > 0 ? nsValid : 0) * kCls;
        for (long long f = tid; f < fvalid; f += BLOCK) {
            const long long sib = f / kCls;
            const int c = (int)(f - sib * kCls);
            gout[f] = s_leaf[s_leafidx[sib] * kLeafPad + c];
        }
    }
}

extern "C" void kernel_launch(void* const* d_in, const int* in_sizes, int n_in,
                              void* d_out, int out_size, void* d_ws, size_t ws_size,
                              hipStream_t stream) {
    // setup_inputs order: X, tree_feature, tree_threshold, tree_left,
    //                     tree_right, tree_value, tree_is_leaf
    const float* X     = (const float*)d_in[0];
    const int*   tfeat = (const int*)d_in[1];
    const float* tthr  = (const float*)d_in[2];
    // tree_left/right are exactly 2i+1 / 2i+2 (complete tree) -> arithmetic.
    // Leaves self-point and are reached only at depth 10 -> fixed 10-step loop.
    const float* tval  = (const float*)d_in[5];
    float* out = (float*)d_out;

    const int n = in_sizes[0] / kFeat;               // 4,000,000
    const int grid = (n + kNS - 1) / kNS;            // 3125, zero tail
    dtree_kernel<<<grid, BLOCK, 0, stream>>>(X, tfeat, tthr, tval, out, n);
}